// Round 16
// baseline (623.477 us; speedup 1.0000x reference)
//
#include <hip/hip_runtime.h>
#include <cstdint>
#include <cstddef>

// ---------------- constants (match reference) ----------------
static constexpr int DIMc = 512;
static constexpr int DHc  = 64;
static constexpr int CHc  = 2;
static constexpr int SHc  = 8;
static constexpr int Bc   = 8;
static constexpr int Tc   = 1024;
static constexpr int Nc   = 2048;
static constexpr int CIc  = CHc * DHc;    // 128
static constexpr int SIc  = SHc * DHc;    // 512
static constexpr int FFc  = 4 * DIMc;     // 2048
static constexpr int RQ   = Bc * Tc;      // 8192 query rows
static constexpr int RL   = Bc * Nc;      // 16384 latent rows
// q scale with log2(e) folded in: attention uses exp2 instead of exp
#define QSCALE 0.1803368801f

typedef short bf16x8 __attribute__((ext_vector_type(8)));
typedef float f32x4  __attribute__((ext_vector_type(4)));

__device__ __forceinline__ ushort f2bf(float f) {
  uint32_t u = __builtin_bit_cast(uint32_t, f);
  u += 0x7fffu + ((u >> 16) & 1u);
  return (ushort)(u >> 16);
}
__device__ __forceinline__ uint32_t packbf2(float a, float b) {
  return (uint32_t)f2bf(a) | ((uint32_t)f2bf(b) << 16);
}
__device__ __forceinline__ float bf2f(ushort h) {
  uint32_t u = ((uint32_t)h) << 16;
  return __builtin_bit_cast(float, u);
}

__device__ __forceinline__ void gload_lds16(const ushort* g, ushort* lds) {
  __builtin_amdgcn_global_load_lds(
      (const __attribute__((address_space(1))) void*)g,
      (__attribute__((address_space(3))) void*)lds, 16, 0, 0);
}

// asm ds_read_b128: invisible to compiler's lgkm/vmcnt tracking (manual waits)
__device__ __forceinline__ bf16x8 ds_read8(const ushort* p) {
  bf16x8 d;
  asm volatile("ds_read_b128 %0, %1"
               : "=v"(d)
               : "v"((const __attribute__((address_space(3))) ushort*)p));
  return d;
}

// fast gelu: tanh form; |err| < 3e-3 abs, well under the bf16 tolerance.
__device__ __forceinline__ float gelu_fast(float g) {
  float u = g * (0.7978845608f + 0.0356774081f * g * g);
  float e = __expf(2.f * u);
  float th = 1.f - 2.f * __builtin_amdgcn_rcpf(1.f + e);
  return 0.5f * g * (1.f + th);
}

// rope rotate: even d: v*c - p*s ; odd d: v*c + p*s  (p = partner lane value)
__device__ __forceinline__ float rope_rot(int odd, float v, float p, float2 cs) {
  return odd ? (v * cs.x + p * cs.y) : (v * cs.x - p * cs.y);
}

// ---------------- cos/sin table prep: dst[i] = (cos(src[i]), sin(src[i])) ----
__global__ __launch_bounds__(256) void trig_prep(const float* __restrict__ src,
    float2* __restrict__ dst, int n) {
  int i = blockIdx.x * 256 + threadIdx.x;
  if (i >= n) return;
  float s, c;
  __sincosf(src[i], &s, &c);
  dst[i] = make_float2(c, s);
}

// ---------------- LayerNorm: one wave per 512-col row, fp32 in -> bf16 out ----
__global__ __launch_bounds__(256) void ln_rows(const float* __restrict__ X,
    const float* __restrict__ w, const float* __restrict__ b,
    ushort* __restrict__ out, int rows) {
  int gw = (int)((blockIdx.x * 256 + threadIdx.x) >> 6);
  int lane = threadIdx.x & 63;
  if (gw >= rows) return;
  const float* xr = X + (size_t)gw * DIMc;
  float4 v0 = *(const float4*)(xr + lane * 8);
  float4 v1 = *(const float4*)(xr + lane * 8 + 4);
  float xv[8] = {v0.x, v0.y, v0.z, v0.w, v1.x, v1.y, v1.z, v1.w};
  float s = 0.f, ss = 0.f;
#pragma unroll
  for (int i = 0; i < 8; i++) { s += xv[i]; ss += xv[i] * xv[i]; }
#pragma unroll
  for (int off = 32; off; off >>= 1) { s += __shfl_xor(s, off); ss += __shfl_xor(ss, off); }
  float mean = s * (1.f / DIMc);
  float var = ss * (1.f / DIMc) - mean * mean;
  float r = rsqrtf(var + 1e-5f);
  int c = lane * 8;
  ushort o[8] __attribute__((aligned(16)));
#pragma unroll
  for (int i = 0; i < 8; i++) o[i] = f2bf((xv[i] - mean) * r * w[c + i] + b[c + i]);
  *(uint4*)(out + (size_t)gw * DIMc + c) = *(const uint4*)o;
}

// ------- LayerNorm x2: one read of X, both layers' weights -> two outputs ----
__global__ __launch_bounds__(256) void ln_rows2(const float* __restrict__ X,
    const float* __restrict__ w, const float* __restrict__ b,
    ushort* __restrict__ out0, ushort* __restrict__ out1, int rows) {
  int gw = (int)((blockIdx.x * 256 + threadIdx.x) >> 6);
  int lane = threadIdx.x & 63;
  if (gw >= rows) return;
  const float* xr = X + (size_t)gw * DIMc;
  float4 v0 = *(const float4*)(xr + lane * 8);
  float4 v1 = *(const float4*)(xr + lane * 8 + 4);
  float xv[8] = {v0.x, v0.y, v0.z, v0.w, v1.x, v1.y, v1.z, v1.w};
  float s = 0.f, ss = 0.f;
#pragma unroll
  for (int i = 0; i < 8; i++) { s += xv[i]; ss += xv[i] * xv[i]; }
#pragma unroll
  for (int off = 32; off; off >>= 1) { s += __shfl_xor(s, off); ss += __shfl_xor(ss, off); }
  float mean = s * (1.f / DIMc);
  float var = ss * (1.f / DIMc) - mean * mean;
  float r = rsqrtf(var + 1e-5f);
  int c = lane * 8;
  ushort o[8] __attribute__((aligned(16)));
#pragma unroll
  for (int i = 0; i < 8; i++) o[i] = f2bf((xv[i] - mean) * r * w[c + i] + b[c + i]);
  *(uint4*)(out0 + (size_t)gw * DIMc + c) = *(const uint4*)o;
#pragma unroll
  for (int i = 0; i < 8; i++) o[i] = f2bf((xv[i] - mean) * r * w[DIMc + c + i] + b[DIMc + c + i]);
  *(uint4*)(out1 + (size_t)gw * DIMc + c) = *(const uint4*)o;
}

// ------------- ALL weight transposes for one layer, one launch ----------------
// wid 5 (ffn_w1): 16-col-granular interleave for the shuffle-free gelu epilogue.
__global__ __launch_bounds__(256) void wtrans_all(
    const float* __restrict__ wq, const float* __restrict__ wkv,
    const float* __restrict__ wo, const float* __restrict__ qkv,
    const float* __restrict__ swo, const float* __restrict__ w1,
    const float* __restrict__ w2, ushort* __restrict__ dst, int layer) {
  constexpr int Ks[7]   = {512, 512, 128, 512, 512, 512, 2048};
  constexpr int Ns[7]   = {128, 256, 512, 1536, 512, 4096, 512};
  constexpr int pre[8]  = {0, 64, 192, 256, 1024, 1280, 3328, 4352};
  constexpr int dOff[7] = {0, 65536, 196608, 262144, 1048576, 1310720, 3407872};
  int bid = blockIdx.x;
  int wid = 0;
#pragma unroll
  for (int i = 1; i < 7; i++) wid += (bid >= pre[i]);
  int tileIdx = bid - pre[wid];
  int K = Ks[wid], N = Ns[wid];
  const float* srcs[7] = {wq, wkv, wo, qkv, swo, w1, w2};
  const float* W = srcs[wid] + (size_t)layer * K * N;
  ushort* Wt = dst + dOff[wid];
  int ntx = N / 32;
  int n0 = (tileIdx % ntx) * 32, k0 = (tileIdx / ntx) * 32;
  __shared__ float tile[32][33];
  int tx = threadIdx.x & 31, ty = threadIdx.x >> 5;
#pragma unroll
  for (int i = 0; i < 32; i += 8)
    tile[ty + i][tx] = W[(size_t)(k0 + ty + i) * N + n0 + tx];
  __syncthreads();
  if (wid == 5) {
#pragma unroll
    for (int i = 0; i < 32; i += 8) {
      int nrow = n0 + ty + i;
      int p = nrow & 2047;
      int rowT = ((p >> 4) << 5) + ((nrow < 2048) ? 0 : 16) + (p & 15);
      Wt[(size_t)rowT * K + k0 + tx] = f2bf(tile[tx][ty + i]);
    }
  } else {
#pragma unroll
    for (int i = 0; i < 32; i += 8)
      Wt[(size_t)(n0 + ty + i) * K + k0 + tx] = f2bf(tile[tx][ty + i]);
  }
}

// ------- 128x128 GEMM, BK=64, single-buffer (proven r3 structure) ------------
// MODE 0: outB = bf16(acc + bias)
// MODE 1: resOut = resIn + acc + bias   (fp32)
// MODE 2: fused FFN gate (16-col interleaved w1T): write bf16(a*gelu(g)), N/2.
// MODE 3: self-qkv fused rope+vt.
template<int MODE>
__global__ __launch_bounds__(256) void gemm128(const ushort* __restrict__ A,
    const ushort* __restrict__ Bt, const float* __restrict__ bias,
    const float* __restrict__ resIn, float* __restrict__ resOut,
    ushort* __restrict__ outB, int M, int N, int K,
    const float2* __restrict__ cs, ushort* __restrict__ vt) {
  __shared__ __align__(16) ushort As[128 * 64];
  __shared__ __align__(16) ushort Bs[128 * 64];
  int t = threadIdx.x, wv = t >> 6, lane = t & 63;
  int bm = blockIdx.y, bn = blockIdx.x;
  int fr = lane & 15, g = lane >> 4;
  int wr = (wv >> 1) * 64, wc = (wv & 1) * 64;
  int srow = wv * 32 + (lane >> 3);
  int sslot = lane & 7;
  const ushort* Abase = A + (size_t)(bm * 128) * K;
  const ushort* Bbase = Bt + (size_t)(bn * 128) * K;

  f32x4 acc[4][4] = {};
  for (int k0 = 0; k0 < K; k0 += 64) {
#pragma unroll
    for (int j = 0; j < 4; j++) {
      int r = srow + j * 8;
      int kc = sslot ^ (r & 7);
      gload_lds16(Abase + (size_t)r * K + k0 + kc * 8, As + (wv * 256 + j * 64) * 8);
      gload_lds16(Bbase + (size_t)r * K + k0 + kc * 8, Bs + (wv * 256 + j * 64) * 8);
    }
    __syncthreads();
#pragma unroll
    for (int ks = 0; ks < 2; ks++) {
      bf16x8 af[4], bf[4];
#pragma unroll
      for (int mm = 0; mm < 4; mm++) {
        int row = wr + mm * 16 + fr;
        af[mm] = *(const bf16x8*)(As + row * 64 + (((ks * 4 + g) ^ (row & 7)) * 8));
      }
#pragma unroll
      for (int nn = 0; nn < 4; nn++) {
        int row = wc + nn * 16 + fr;
        bf[nn] = *(const bf16x8*)(Bs + row * 64 + (((ks * 4 + g) ^ (row & 7)) * 8));
      }
#pragma unroll
      for (int mm = 0; mm < 4; mm++)
#pragma unroll
        for (int nn = 0; nn < 4; nn++)
          acc[mm][nn] = __builtin_amdgcn_mfma_f32_16x16x32_bf16(af[mm], bf[nn], acc[mm][nn], 0, 0, 0);
    }
    __syncthreads();
  }

  if (MODE == 2) {
    int NH = N >> 1;
#pragma unroll
    for (int mm = 0; mm < 4; mm++)
#pragma unroll
      for (int np = 0; np < 2; np++) {
        int ocol = bn * 64 + (wc >> 1) + np * 16 + fr;
        float ba = bias[ocol];
        float bg = bias[NH + ocol];
#pragma unroll
        for (int i = 0; i < 4; i++) {
          int gr = bm * 128 + wr + mm * 16 + g * 4 + i;
          float a = acc[mm][np * 2][i] + ba;
          float gv = acc[mm][np * 2 + 1][i] + bg;
          outB[(size_t)gr * NH + ocol] = f2bf(a * gelu_fast(gv));
        }
      }
  } else if (MODE == 3) {
    if (bn * 128 < 1024) {   // q/k block: fused rope (QSCALE on q)
#pragma unroll
      for (int mm = 0; mm < 4; mm++)
#pragma unroll
        for (int nn = 0; nn < 4; nn++) {
          int gc = bn * 128 + wc + nn * 16 + fr;
          int d = gc & 63;
          float sc = (gc < 512) ? QSCALE : 1.f;
#pragma unroll
          for (int i = 0; i < 4; i++) {
            int gr = bm * 128 + wr + mm * 16 + g * 4 + i;
            float val = acc[mm][nn][i];
            float prt = __shfl_xor(val, 1);
            float2 csv = cs[(size_t)gr * 64 + d];
            outB[(size_t)gr * N + gc] = f2bf(rope_rot(fr & 1, val, prt, csv) * sc);
          }
        }
    } else {                 // v block: transposed store to vt[b][ch][t]
#pragma unroll
      for (int mm = 0; mm < 4; mm++)
#pragma unroll
        for (int nn = 0; nn < 4; nn++) {
          int gc = bn * 128 + wc + nn * 16 + fr;
          int ch = gc - 1024;
          int gr0 = bm * 128 + wr + mm * 16 + g * 4;
          int bb = gr0 >> 10, t0 = gr0 & 1023;
          uint2 w;
          w.x = packbf2(acc[mm][nn][0], acc[mm][nn][1]);
          w.y = packbf2(acc[mm][nn][2], acc[mm][nn][3]);
          *(uint2*)(vt + ((size_t)bb * 512 + ch) * 1024 + t0) = w;
        }
    }
  } else {
#pragma unroll
    for (int mm = 0; mm < 4; mm++)
#pragma unroll
      for (int nn = 0; nn < 4; nn++)
#pragma unroll
        for (int i = 0; i < 4; i++) {
          int gr = bm * 128 + wr + mm * 16 + g * 4 + i;
          int gc = bn * 128 + wc + nn * 16 + fr;
          float val = acc[mm][nn][i] + (bias ? bias[gc] : 0.f);
          if (MODE == 0) outB[(size_t)gr * N + gc] = f2bf(val);
          else resOut[(size_t)gr * N + gc] = resIn[(size_t)gr * N + gc] + val;
        }
  }
}

// ------- 256x256 GEMM, BK=64, 8-wave 4-phase COUNTED-vmcnt pipeline ----------
// (w1 only; measured ≈ gemm128<2> rate, kept from the 628 µs configuration)
__global__ __launch_bounds__(512, 2) void gemm256_gelu(
    const ushort* __restrict__ A, const ushort* __restrict__ Bt,
    const float* __restrict__ bias, ushort* __restrict__ outB,
    int M, int N, int K) {
  __shared__ __align__(16) ushort As[2][256 * 64];   // 64 KB
  __shared__ __align__(16) ushort Bs[2][256 * 64];   // 64 KB
  int t = threadIdx.x, wv = t >> 6, lane = t & 63;
  int bm = blockIdx.y, bn = blockIdx.x;
  int fr = lane & 15, g = lane >> 4;
  int wr = (wv >> 2) * 128, wc = (wv & 3) * 64;      // 2M x 4N wave grid
  int srow = wv * 32 + (lane >> 3);
  int sslot = lane & 7;
  const ushort* Abase = A + (size_t)(bm * 256) * K;
  const ushort* Bbase = Bt + (size_t)(bn * 256) * K;

  f32x4 acc[8][4] = {};
  int nt = K >> 6;   // 8 for K=512

#define STG256(buf, kt)                                                       \
  {                                                                           \
    _Pragma("unroll")                                                         \
    for (int j = 0; j < 4; j++) {                                             \
      int r = srow + j * 8;                                                   \
      int kc = sslot ^ (r & 7);                                               \
      gload_lds16(Abase + (size_t)r * K + (kt) * 64 + kc * 8,                 \
                  &As[buf][(wv * 256 + j * 64) * 8]);                         \
      gload_lds16(Bbase + (size_t)r * K + (kt) * 64 + kc * 8,                 \
                  &Bs[buf][(wv * 256 + j * 64) * 8]);                         \
    }                                                                         \
  }

  STG256(0, 0);
  STG256(1, 1);

  for (int tt = 0; tt < nt; tt++) {
    int cur = tt & 1;
    if (tt + 1 < nt) asm volatile("s_waitcnt vmcnt(8)" ::: "memory");
    else             asm volatile("s_waitcnt vmcnt(0)" ::: "memory");
    __builtin_amdgcn_s_barrier();
    const ushort* Ac = As[cur];
    const ushort* Bc = Bs[cur];
#pragma unroll
    for (int ph = 0; ph < 4; ph++) {
      const int mh = ph >> 1, nh = ph & 1;
      bf16x8 af[2][4], bf[2][2];
#pragma unroll
      for (int ks = 0; ks < 2; ks++) {
#pragma unroll
        for (int mi = 0; mi < 4; mi++) {
          int row = wr + (mh * 4 + mi) * 16 + fr;
          af[ks][mi] = ds_read8(Ac + row * 64 + (((ks * 4 + g) ^ (row & 7)) * 8));
        }
#pragma unroll
        for (int ni = 0; ni < 2; ni++) {
          int row = wc + (nh * 2 + ni) * 16 + fr;
          bf[ks][ni] = ds_read8(Bc + row * 64 + (((ks * 4 + g) ^ (row & 7)) * 8));
        }
      }
      asm volatile("s_waitcnt lgkmcnt(0)" ::: "memory");
      __builtin_amdgcn_sched_barrier(0);
      __builtin_amdgcn_s_setprio(1);
#pragma unroll
      for (int ks = 0; ks < 2; ks++)
#pragma unroll
        for (int mi = 0; mi < 4; mi++)
#pragma unroll
          for (int ni = 0; ni < 2; ni++)
            acc[mh * 4 + mi][nh * 2 + ni] = __builtin_amdgcn_mfma_f32_16x16x32_bf16(
                af[ks][mi], bf[ks][ni], acc[mh * 4 + mi][nh * 2 + ni], 0, 0, 0);
      __builtin_amdgcn_s_setprio(0);
      __builtin_amdgcn_s_barrier();
    }
    if (tt + 2 < nt) STG256(cur, tt + 2);
  }
#undef STG256

  int NH = N >> 1;
#pragma unroll
  for (int mf = 0; mf < 8; mf++)
#pragma unroll
    for (int np = 0; np < 2; np++) {
      int ocol = bn * 128 + (wc >> 1) + np * 16 + fr;
      float ba = bias[ocol];
      float bg = bias[NH + ocol];
#pragma unroll
      for (int i = 0; i < 4; i++) {
        int gr = bm * 256 + wr + mf * 16 + g * 4 + i;
        float a = acc[mf][np * 2][i] + ba;
        float gv = acc[mf][np * 2 + 1][i] + bg;
        outB[(size_t)gr * NH + ocol] = f2bf(a * gelu_fast(gv));
      }
    }
}

// ------- 128x64 GEMM, BK=64, single-buffer, 24 KB LDS (high occupancy) -------
template<int MODE>
__global__ __launch_bounds__(256) void gemm128x64(const ushort* __restrict__ A,
    const ushort* __restrict__ Bt, const float* __restrict__ bias,
    const float* __restrict__ resIn, float* __restrict__ resOut,
    ushort* __restrict__ outB, int M, int N, int K,
    const float2* __restrict__ cs, ushort* __restrict__ vt) {
  __shared__ __align__(16) ushort As[128 * 64];   // 16 KB
  __shared__ __align__(16) ushort Bs[64 * 64];    //  8 KB
  int t = threadIdx.x, wv = t >> 6, lane = t & 63;
  int bm = blockIdx.y, bn = blockIdx.x;
  int fr = lane & 15, g = lane >> 4;
  int wr = (wv >> 1) * 64, wc = (wv & 1) * 32;
  const ushort* Abase = A + (size_t)(bm * 128) * K;
  const ushort* Bbase = Bt + (size_t)(bn * 64) * K;

  f32x4 acc[4][2] = {};
  for (int k0 = 0; k0 < K; k0 += 64) {
#pragma unroll
    for (int j = 0; j < 4; j++) {
      int c = j * 256 + wv * 64 + lane;
      int r = c >> 3, s = c & 7;
      int kc = s ^ (r & 7);
      gload_lds16(Abase + (size_t)r * K + k0 + kc * 8, As + (j * 256 + wv * 64) * 8);
      if (j < 2)
        gload_lds16(Bbase + (size_t)r * K + k0 + kc * 8, Bs + (j * 256 + wv * 64) * 8);
    }
    __syncthreads();
#pragma unroll
    for (int ks = 0; ks < 2; ks++) {
      bf16x8 af[4], bf[2];
#pragma unroll
      for (int mm = 0; mm < 4; mm++) {
        int row = wr + mm * 16 + fr;
        af[mm] = *(const bf16x8*)(As + row * 64 + (((ks * 4 + g) ^ (row & 7)) * 8));
      }
#pragma unroll
      for (int nn = 0; nn < 2; nn++) {
        int row = wc + nn * 16 + fr;
        bf[nn] = *(const bf16x8*)(Bs + row * 64 + (((ks * 4 + g) ^ (row & 7)) * 8));
      }
#pragma unroll
      for (int mm = 0; mm < 4; mm++)
#pragma unroll
        for (int nn = 0; nn < 2; nn++)
          acc[mm][nn] = __builtin_amdgcn_mfma_f32_16x16x32_bf16(af[mm], bf[nn], acc[mm][nn], 0, 0, 0);
    }
    __syncthreads();
  }

  if (MODE == 3) {
    if (bn * 64 < 128) {     // k block: fused rope (lat table)
#pragma unroll
      for (int mm = 0; mm < 4; mm++)
#pragma unroll
        for (int nn = 0; nn < 2; nn++) {
          int gc = bn * 64 + wc + nn * 16 + fr;
          int d = gc & 63;
#pragma unroll
          for (int i = 0; i < 4; i++) {
            int gr = bm * 128 + wr + mm * 16 + g * 4 + i;
            float val = acc[mm][nn][i];
            float prt = __shfl_xor(val, 1);
            float2 csv = cs[(size_t)gr * 64 + d];
            outB[(size_t)gr * N + gc] = f2bf(rope_rot(fr & 1, val, prt, csv));
          }
        }
    } else {                 // v block: transposed store
#pragma unroll
      for (int mm = 0; mm < 4; mm++)
#pragma unroll
        for (int nn = 0; nn < 2; nn++) {
          int gc = bn * 64 + wc + nn * 16 + fr;
          int ch = gc - 128;
          int gr0 = bm * 128 + wr + mm * 16 + g * 4;
          int bb = gr0 >> 11, t0 = gr0 & 2047;
          uint2 w;
          w.x = packbf2(acc[mm][nn][0], acc[mm][nn][1]);
          w.y = packbf2(acc[mm][nn][2], acc[mm][nn][3]);
          *(uint2*)(vt + ((size_t)bb * 128 + ch) * 2048 + t0) = w;
        }
    }
  } else {
#pragma unroll
    for (int mm = 0; mm < 4; mm++)
#pragma unroll
      for (int nn = 0; nn < 2; nn++)
#pragma unroll
        for (int i = 0; i < 4; i++) {
          int gr = bm * 128 + wr + mm * 16 + g * 4 + i;
          int gc = bn * 64 + wc + nn * 16 + fr;
          float val = acc[mm][nn][i] + (bias ? bias[gc] : 0.f);
          if (MODE == 0) outB[(size_t)gr * N + gc] = f2bf(val);
          else resOut[(size_t)gr * N + gc] = resIn[(size_t)gr * N + gc] + val;
        }
  }
}

// ------- 64x64 GEMM with fused rope (QSCALE) epilogue (cross-q only) ---------
__global__ __launch_bounds__(256) void gemm64_rope(const ushort* __restrict__ A,
    const ushort* __restrict__ Bt, ushort* __restrict__ outB,
    const float2* __restrict__ cs, int M, int N, int K) {
  __shared__ __align__(16) ushort As[64][40];
  __shared__ __align__(16) ushort Bs[64][40];
  int t = threadIdx.x;
  int bm = blockIdx.y, bn = blockIdx.x;
  int row = t >> 2, kc = (t & 3) << 3;
  const ushort* aG = A + (size_t)(bm * 64 + row) * K + kc;
  const ushort* bG = Bt + (size_t)(bn * 64 + row) * K + kc;
  int wv = t >> 6, lane = t & 63;
  int wr = (wv >> 1) * 32, wc = (wv & 1) * 32;
  int fr = lane & 15, fk = (lane >> 4) << 3;
  f32x4 acc[2][2] = {};
  for (int k0 = 0; k0 < K; k0 += 32) {
    *(uint4*)&As[row][kc] = *(const uint4*)(aG + k0);
    *(uint4*)&Bs[row][kc] = *(const uint4*)(bG + k0);
    __syncthreads();
    bf16x8 a0 = *(const bf16x8*)&As[wr + fr][fk];
    bf16x8 a1 = *(const bf16x8*)&As[wr + 16 + fr][fk];
    bf16x8 b0 = *(const bf16x8*)&Bs[wc + fr][fk];
    bf16x8 b1 = *(const bf16x8*)&Bs[wc + 16 + fr][fk];
    acc[0][0] = __builtin_amdgcn_mfma_f32_16x16x32_bf16(a0, b0, acc[0][0], 0, 0, 0);
    acc[0][1] = __builtin_amdgcn_mfma_f32_16x16x32_bf16(a0, b1, acc[0][1], 0, 0, 0);
    acc[1][0] = __builtin_amdgcn_mfma_f32_16x16x32_bf16(a1, b0, acc[1][0], 0, 0, 0);
    acc[1][1] = __builtin_amdgcn_mfma_f32_16x16x32_bf16(a1, b1, acc[1][1], 0, 0, 0);
    __syncthreads();
  }
  int cr0 = wr + ((lane >> 4) << 2);
  int cc0 = wc + fr;
#pragma unroll
  for (int mm = 0; mm < 2; mm++)
#pragma unroll
    for (int nn = 0; nn < 2; nn++) {
      int gc = bn * 64 + cc0 + nn * 16;
      int d = gc & 63;
#pragma unroll
      for (int i = 0; i < 4; i++) {
        int gr = bm * 64 + cr0 + mm * 16 + i;
        float val = acc[mm][nn][i];
        float prt = __shfl_xor(val, 1);
        float2 csv = cs[(size_t)gr * 64 + d];
        outB[(size_t)gr * N + gc] = f2bf(rope_rot(fr & 1, val, prt, csv) * QSCALE);
      }
    }
}

// ====== shared attention tile body (KVBLK=128, exp2 softmax) =================
// Ks [128 kv][64 d] swizzled; Vs [64 d][128 kv] swizzled; Ps row stride 136.
#define ATTN_STAGE_TILE(k0)                                                   \
  {                                                                           \
    _Pragma("unroll")                                                         \
    for (int i = 0; i < 4; i++) {                                             \
      int id = t + i * 256;                                                   \
      int r = id >> 3, c = id & 7;                                            \
      uint4 kval = *(const uint4*)(K + (size_t)(b * NK + (k0) + r) * kStride  \
                                   + kOff + h * 64 + c * 8);                  \
      *(uint4*)(Ks + r * 64 + ((c ^ (r & 7)) * 8)) = kval;                    \
      int rv = id >> 4, cv = id & 15;                                         \
      uint4 vval = *(const uint4*)(Vt + ((size_t)b * HD + h * 64 + rv) * NK   \
                                   + (k0) + cv * 8);                          \
      *(uint4*)(Vs + rv * 128 + ((cv ^ (rv & 7)) * 8)) = vval;                \
    }                                                                         \
  }

#define ATTN_TILE_BODY(MASKED)                                                \
  {                                                                           \
    f32x4 s[8];                                                               \
    _Pragma("unroll")                                                         \
    for (int nn = 0; nn < 8; nn++) {                                          \
      int row = nn * 16 + fr;                                                 \
      bf16x8 kf0 = *(const bf16x8*)(Ks + row * 64 + ((g ^ (fr & 7)) * 8));    \
      bf16x8 kf1 = *(const bf16x8*)(Ks + row * 64 + (((4 + g) ^ (fr & 7)) * 8)); \
      f32x4 z = {};                                                           \
      z = __builtin_amdgcn_mfma_f32_16x16x32_bf16(kf0, qlo, z, 0, 0, 0);      \
      z = __builtin_amdgcn_mfma_f32_16x16x32_bf16(kf1, qhi, z, 0, 0, 0);      \
      s[nn] = z;                                                              \
    }                                                                         \
    if (MASKED) {                                                             \
      _Pragma("unroll")                                                       \
      for (int nn = 0; nn < 8; nn++)                                          \
        _Pragma("unroll")                                                     \
        for (int i = 0; i < 4; i++)                                           \
          if (k0 + nn * 16 + g * 4 + i > qw + fr) s[nn][i] = -1e30f;          \
    }                                                                         \
    float tm = s[0][0];                                                       \
    _Pragma("unroll")                                                         \
    for (int nn = 0; nn < 8; nn++)                                            \
      _Pragma("unroll")                                                       \
      for (int i = 0; i < 4; i++) tm = fmaxf(tm, s[nn][i]);                   \
    tm = fmaxf(tm, __shfl_xor(tm, 16));                                       \
    tm = fmaxf(tm, __shfl_xor(tm, 32));                                       \
    float mnew = fmaxf(m_run, tm);                                            \
    float corr = exp2f(m_run - mnew);                                         \
    float ps = 0.f;                                                           \
    _Pragma("unroll")                                                         \
    for (int nn = 0; nn < 8; nn++)                                            \
      _Pragma("unroll")                                                       \
      for (int i = 0; i < 4; i++) {                                           \
        float p = exp2f(s[nn][i] - mnew);                                     \
        s[nn][i] = p;                                                         \
        ps += p;                                                              \
      }                                                                       \
    ps += __shfl_xor(ps, 16);                                                 \
    ps += __shfl_xor(ps, 32);                                                 \
    l_run = l_run * corr + ps;                                                \
    m_run = mnew;                                                             \
    _Pragma("unroll")                                                         \
    for (int dd = 0; dd < 4; dd++) o_acc[dd] *= corr;                         \
    _Pragma("unroll")                                                         \
    for (int nn = 0; nn < 8; nn++)                                            \
      _Pragma("unroll")                                                       \
      for (int p = 0; p < 2; p++)                                             \
        Pw[fr * 68 + nn * 8 + g * 2 + p] = packbf2(s[nn][2 * p], s[nn][2 * p + 1]); \
    _Pragma("unroll")                                                         \
    for (int ks = 0; ks < 4; ks++) {                                          \
      bf16x8 pa = *(const bf16x8*)(&Ps[wv][fr * 136 + ks * 32 + g * 8]);      \
      _Pragma("unroll")                                                       \
      for (int dd = 0; dd < 4; dd++) {                                        \
        int row = dd * 16 + fr;                                               \
        bf16x8 vf = *(const bf16x8*)(Vs + row * 128 + (((ks * 4 + g) ^ (fr & 7)) * 8)); \
        o_acc[dd] = __builtin_amdgcn_mfma_f32_16x16x32_bf16(vf, pa, o_acc[dd], 0, 0, 0); \
      }                                                                       \
    }                                                                         \
  }

// ---------------- causal flash attention, KVBLK=128 --------------------------
__global__ __launch_bounds__(256) void attn_causal(
    const ushort* __restrict__ Q, const ushort* __restrict__ K,
    const ushort* __restrict__ Vt, ushort* __restrict__ O,
    int qStride, int kStride, int kOff, int oStride,
    int Tq, int NK, int H) {
  __shared__ __align__(16) ushort Ks[128 * 64];
  __shared__ __align__(16) ushort Vs[64 * 128];
  __shared__ __align__(16) ushort Ps[4][16 * 136];
  int b = blockIdx.z, h = blockIdx.y;
  int qt = (int)gridDim.x - 1 - (int)blockIdx.x;   // big blocks first
  int t = threadIdx.x, wv = t >> 6, lane = t & 63;
  int g = lane >> 4, fr = lane & 15;
  int qw = qt * 64 + wv * 16;
  int HD = H * 64;

  const ushort* qrow = Q + (size_t)(b * Tq + qw + fr) * qStride + h * 64;
  bf16x8 qlo = *(const bf16x8*)(qrow + g * 8);
  bf16x8 qhi = *(const bf16x8*)(qrow + 32 + g * 8);

  f32x4 o_acc[4] = {};
  float m_run = -1e30f, l_run = 0.f;
  uint32_t* Pw = (uint32_t*)&Ps[wv][0];
  int ntiles = (qt >> 1) + 1;
  for (int kt = 0; kt < ntiles; kt++) {
    int k0 = kt * 128;
    __syncthreads();
    ATTN_STAGE_TILE(k0);
    __syncthreads();
    if (k0 + 127 > qw) { ATTN_TILE_BODY(1); }
    else               { ATTN_TILE_BODY(0); }
  }
  float rl = 1.f / l_run;
  ushort* obase = O + (size_t)(b * Tq + qw + fr) * oStride + h * 64;
#pragma unroll
  for (int dd = 0; dd < 4; dd++) {
    uint2 w;
    w.x = packbf2(o_acc[dd][0] * rl, o_acc[dd][1] * rl);
    w.y = packbf2(o_acc[dd][2] * rl, o_acc[dd][3] * rl);
    *(uint2*)(obase + dd * 16 + g * 4) = w;
  }
}

// -------- split-KV flash attention (no mask), KVBLK=128, 2 splits ------------
// grid (Tq/64, H*2, B); split sp covers tiles [sp*NK/256, (sp+1)*NK/256).
__global__ __launch_bounds__(256) void attn_split(
    const ushort* __restrict__ Q, const ushort* __restrict__ K,
    const ushort* __restrict__ Vt, float* __restrict__ Opart,
    float2* __restrict__ mlpart,
    int qStride, int kStride, int kOff, int Tq, int NK, int H) {
  __shared__ __align__(16) ushort Ks[128 * 64];
  __shared__ __align__(16) ushort Vs[64 * 128];
  __shared__ __align__(16) ushort Ps[4][16 * 136];
  int b = blockIdx.z;
  int h = blockIdx.y >> 1, sp = blockIdx.y & 1;
  int qt = blockIdx.x;
  int t = threadIdx.x, wv = t >> 6, lane = t & 63;
  int g = lane >> 4, fr = lane & 15;
  int qw = qt * 64 + wv * 16;
  int HD = H * 64;
  int half = NK / 256;   // tiles of 128 per split
  int ktbeg = sp * half, ktend = ktbeg + half;

  const ushort* qrow = Q + (size_t)(b * Tq + qw + fr) * qStride + h * 64;
  bf16x8 qlo = *(const bf16x8*)(qrow + g * 8);
  bf16x8 qhi = *(const bf16x8*)(qrow + 32 + g * 8);

  f32x4 o_acc[4] = {};
  float m_run = -1e30f, l_run = 0.f;
  uint32_t* Pw = (uint32_t*)&Ps[wv][0];
  for (int kt = ktbeg; kt < ktend; kt++) {
    int k0 = kt * 128;
    __syncthreads();
    ATTN_STAGE_TILE(k0);
    __syncthreads();
    ATTN_TILE_BODY(0);
  }
  size_t pslot = ((size_t)(b * H + h) * 2 + sp) * Tq + qw + fr;
  float* obase = Opart + pslot * 64;
#pragma unroll
  for (int dd = 0; dd < 4; dd++)
    *(float4*)(obase + dd * 16 + g * 4) = *(float4*)&o_acc[dd];
  if (g == 0) mlpart[pslot] = make_float2(m_run, l_run);
}

// -------- combine 2 splits (exp2 domain) -------------------------------------
__global__ __launch_bounds__(256) void attn_combine(
    const float* __restrict__ Opart, const float2* __restrict__ mlpart,
    ushort* __restrict__ O, int Tq, int H, int oStride) {
  int idx = blockIdx.x * 256 + threadIdx.x;     // B*H*Tq*16 threads (4 d each)
  int dq = (idx & 15) * 4;
  int tt = (idx >> 4) & (Tq - 1);
  int hh = idx >> 14;                           // b*H+h  (16*Tq = 2^14)
  int b = hh / H, h = hh % H;
  size_t base0 = (((size_t)hh * 2 + 0) * Tq + tt) * 64 + dq;
  size_t base1 = base0 + (size_t)Tq * 64;
  float2 ml0 = mlpart[((size_t)hh * 2 + 0) * Tq + tt];
  float2 ml1 = mlpart[((size_t)hh * 2 + 1) * Tq + tt];
  float M = fmaxf(ml0.x, ml1.x);
  float w0 = exp2f(ml0.x - M), w1 = exp2f(ml1.x - M);
  float rl = 1.f / (w0 * ml0.y + w1 * ml1.y);
  float4 o0 = *(const float4*)(Opart + base0);
  float4 o1 = *(const float4*)(Opart + base1);
  uint2 w;
  w.x = packbf2((w0 * o0.x + w1 * o1.x) * rl, (w0 * o0.y + w1 * o1.y) * rl);
  w.y = packbf2((w0 * o0.z + w1 * o1.z) * rl, (w0 * o0.w + w1 * o1.w) * rl);
  *(uint2*)(O + (size_t)(b * Tq + tt) * oStride + h * 64 + dq) = w;
}

// ---------------- orchestration ----------------------------------------------
extern "C" void kernel_launch(void* const* d_in, const int* in_sizes, int n_in,
                              void* d_out, int out_size, void* d_ws, size_t ws_size,
                              hipStream_t stream) {
  const float* bin_queries = (const float*)d_in[0];
  const float* bin_time    = (const float*)d_in[1];
  const float* latents     = (const float*)d_in[2];
  const float* lat_time    = (const float*)d_in[3];
  const float* ca_lnq_w = (const float*)d_in[4];
  const float* ca_lnq_b = (const float*)d_in[5];
  const float* ca_lnc_w = (const float*)d_in[6];
  const float* ca_lnc_b = (const float*)d_in[7];
  const float* ca_wq  = (const float*)d_in[8];
  const float* ca_wkv = (const float*)d_in[9];
  const float* ca_wo  = (const float*)d_in[10];
  const float* ca_bo  = (const float*)d_in[11];
  const float* sa_ln_w = (const float*)d_in[12];
  const float* sa_ln_b = (const float*)d_in[13];
  const float* sa_wqkv = (const float*)d_in[14];
  const float* sa_wo   = (const float*)d_in[15];
  const float* sa_bo   = (const float*)d_in[16];
  const float* ffn_ln_w = (const float*)d_in[17];
  const float* ffn_ln_b = (const float*)d_in[18];
  const float* ffn_w1 = (const float*)d_in[19];
  const float* ffn_b1 = (const float*)d_in[20];
  const float* ffn_w2 = (const float*)d_in[21];
  const float* ffn_b2 = (const float*)d_in[22];

  constexpr size_t X_BYTES = (size_t)RQ * DIMc * 4;
  char* ws = (char*)d_ws;
  float* x = (float*)ws;
  char* A0 = ws + X_BYTES;
  // cross-attn phase
  ushort* cn     = (ushort*)(A0);               // layer-0 cn (arena, reused later)
  ushort* ca_xn  = (ushort*)(A0 + 16777216);
  ushort* qbuf   = (ushort*)(A0 + 25165824);
  ushort* kv     = (ushort*)(A0 + 27262976);
  ushort* ca_att = (ushort*)(A0 + 35651584);
  ushort* vt_c   = (ushort*)(A0 + 37748736);
  // self-attn phase (reuses arena)
  ushort* sa_xn  = (ushort*)(A0);
  ushort* qkv    = (ushort*)(A0 + 8388608);
  ushort* sa_att = (ushort*)(A0 + 33554432);
  ushort* vt_s   = (ushort*)(A0 + 41943040);
  // ffn phase (reuses arena)
  ushort* hb     = (ushort*)(A0);
  ushort* ag     = (ushort*)(A0 + 8388608);
  // persistent region (never overwritten by phase arena)
  float2* csQ    = (float2*)(A0 + 62914560);    // 4 MB
  float2* csL    = (float2*)(A0 + 67108864);    // 8 MB
  ushort* cn2    = (ushort*)(A0 + 79691776);    // 16 MB (layer-1 cn)
  float*  Opart  = (float*)(A0 + 96468992);     // 8 MB (split partials)
  float2* mlpart = (float2*)(A0 + 104857600);   // 256 KB
  // bf16 transposed weights for the current layer
  char* W0 = A0 + 109051904;
  ushort* wbase = (ushort*)W0;
  ushort* wqT  = wbase;
  ushort* wkvT = wbase + 65536;
  ushort* woT  = wbase + 196608;
  ushort* qkvT = wbase + 262144;
  ushort* swoT = wbase + 1048576;
  ushort* w1T  = wbase + 1310720;
  ushort* w2T  = wbase + 3407872;

  trig_prep<<<(RQ * 64) / 256, 256, 0, stream>>>(bin_time, csQ, RQ * 64);
  trig_prep<<<(RL * 64) / 256, 256, 0, stream>>>(lat_time, csL, RL * 64);
  // both layers' latent LN in one pass over latents
  ln_rows2<<<RL / 4, 256, 0, stream>>>(latents, ca_lnc_w, ca_lnc_b, cn, cn2, RL);

  for (int l = 0; l < 2; l++) {
    wtrans_all<<<4352, 256, 0, stream>>>(ca_wq, ca_wkv, ca_wo, sa_wqkv, sa_wo,
                                         ffn_w1, ffn_w2, wbase, l);

    // ---- cross attention (split-KV, 2 splits) ----
    const float* xin = (l == 0) ? bin_queries : x;
    const ushort* cnl = (l == 0) ? cn : cn2;
    ln_rows<<<RQ / 4, 256, 0, stream>>>(xin, ca_lnq_w + l * DIMc, ca_lnq_b + l * DIMc, ca_xn, RQ);
    gemm64_rope<<<dim3(CIc / 64, RQ / 64), 256, 0, stream>>>(ca_xn, wqT, qbuf, csQ, RQ, CIc, DIMc);
    gemm128x64<3><<<dim3(2 * CIc / 64, RL / 128), 256, 0, stream>>>(cnl, wkvT, nullptr,
        nullptr, nullptr, kv, RL, 2 * CIc, DIMc, csL, vt_c);
    attn_split<<<dim3(Tc / 64, CHc * 2, Bc), 256, 0, stream>>>(qbuf, kv, vt_c,
        Opart, mlpart, CIc, 2 * CIc, 0, Tc, Nc, CHc);
    attn_combine<<<(Bc * CHc * Tc * 16) / 256, 256, 0, stream>>>(Opart, mlpart,
        ca_att, Tc, CHc, CIc);
    gemm128x64<1><<<dim3(DIMc / 64, RQ / 128), 256, 0, stream>>>(ca_att, woT, ca_bo + l * DIMc,
        xin, x, nullptr, RQ, DIMc, CIc, nullptr, nullptr);

    // ---- self attention (causal, KVBLK=128) ----
    ln_rows<<<RQ / 4, 256, 0, stream>>>(x, sa_ln_w + l * DIMc, sa_ln_b + l * DIMc, sa_xn, RQ);
    gemm128<3><<<dim3(3 * SIc / 128, RQ / 128), 256, 0, stream>>>(sa_xn, qkvT, nullptr,
        nullptr, nullptr, qkv, RQ, 3 * SIc, DIMc, csQ, vt_s);
    attn_causal<<<dim3(Tc / 64, SHc, Bc), 256, 0, stream>>>(qkv, qkv, vt_s, sa_att,
        3 * SIc, 3 * SIc, SIc, SIc, Tc, Tc, SHc);
    gemm128x64<1><<<dim3(DIMc / 64, RQ / 128), 256, 0, stream>>>(sa_att, swoT, sa_bo + l * DIMc,
        x, x, nullptr, RQ, DIMc, SIc, nullptr, nullptr);

    // ---- FFN: w1 on the 8-wave counted-vmcnt 256x256 pipeline ----
    ln_rows<<<RQ / 4, 256, 0, stream>>>(x, ffn_ln_w + l * DIMc, ffn_ln_b + l * DIMc, hb, RQ);
    gemm256_gelu<<<dim3(2 * FFc / 256, RQ / 256), 512, 0, stream>>>(hb, w1T,
        ffn_b1 + (size_t)l * 2 * FFc, ag, RQ, 2 * FFc, DIMc);
    float* resOut = (l == 1) ? (float*)d_out : x;
    gemm128x64<1><<<dim3(DIMc / 64, RQ / 128), 256, 0, stream>>>(ag, w2T, ffn_b2 + l * DIMc,
        x, resOut, nullptr, RQ, DIMc, FFc, nullptr, nullptr);
  }
}

// Round 17
// 621.885 us; speedup vs baseline: 1.0026x; 1.0026x over previous
//
#include <hip/hip_runtime.h>
#include <cstdint>
#include <cstddef>

// ---------------- constants (match reference) ----------------
static constexpr int DIMc = 512;
static constexpr int DHc  = 64;
static constexpr int CHc  = 2;
static constexpr int SHc  = 8;
static constexpr int Bc   = 8;
static constexpr int Tc   = 1024;
static constexpr int Nc   = 2048;
static constexpr int CIc  = CHc * DHc;    // 128
static constexpr int SIc  = SHc * DHc;    // 512
static constexpr int FFc  = 4 * DIMc;     // 2048
static constexpr int RQ   = Bc * Tc;      // 8192 query rows
static constexpr int RL   = Bc * Nc;      // 16384 latent rows

typedef short bf16x8 __attribute__((ext_vector_type(8)));
typedef float f32x4  __attribute__((ext_vector_type(4)));

__device__ __forceinline__ ushort f2bf(float f) {
  uint32_t u = __builtin_bit_cast(uint32_t, f);
  u += 0x7fffu + ((u >> 16) & 1u);
  return (ushort)(u >> 16);
}
__device__ __forceinline__ uint32_t packbf2(float a, float b) {
  return (uint32_t)f2bf(a) | ((uint32_t)f2bf(b) << 16);
}
__device__ __forceinline__ float bf2f(ushort h) {
  uint32_t u = ((uint32_t)h) << 16;
  return __builtin_bit_cast(float, u);
}

__device__ __forceinline__ void gload_lds16(const ushort* g, ushort* lds) {
  __builtin_amdgcn_global_load_lds(
      (const __attribute__((address_space(1))) void*)g,
      (__attribute__((address_space(3))) void*)lds, 16, 0, 0);
}

// asm ds_read_b128: invisible to compiler's lgkm/vmcnt tracking (manual waits)
__device__ __forceinline__ bf16x8 ds_read8(const ushort* p) {
  bf16x8 d;
  asm volatile("ds_read_b128 %0, %1"
               : "=v"(d)
               : "v"((const __attribute__((address_space(3))) ushort*)p));
  return d;
}

// fast gelu: tanh form; |err| < 3e-3 abs, well under the bf16 tolerance.
__device__ __forceinline__ float gelu_fast(float g) {
  float u = g * (0.7978845608f + 0.0356774081f * g * g);
  float e = __expf(2.f * u);
  float th = 1.f - 2.f * __builtin_amdgcn_rcpf(1.f + e);
  return 0.5f * g * (1.f + th);
}

// rope rotate: even d: v*c - p*s ; odd d: v*c + p*s  (p = partner lane value)
__device__ __forceinline__ float rope_rot(int odd, float v, float p, float2 cs) {
  return odd ? (v * cs.x + p * cs.y) : (v * cs.x - p * cs.y);
}

// ---------------- cos/sin table prep: dst[i] = (cos(src[i]), sin(src[i])) ----
__global__ __launch_bounds__(256) void trig_prep(const float* __restrict__ src,
    float2* __restrict__ dst, int n) {
  int i = blockIdx.x * 256 + threadIdx.x;
  if (i >= n) return;
  float s, c;
  __sincosf(src[i], &s, &c);
  dst[i] = make_float2(c, s);
}

// ---------------- LayerNorm: one wave per 512-col row, fp32 in -> bf16 out ----
__global__ __launch_bounds__(256) void ln_rows(const float* __restrict__ X,
    const float* __restrict__ w, const float* __restrict__ b,
    ushort* __restrict__ out, int rows) {
  int gw = (int)((blockIdx.x * 256 + threadIdx.x) >> 6);
  int lane = threadIdx.x & 63;
  if (gw >= rows) return;
  const float* xr = X + (size_t)gw * DIMc;
  float4 v0 = *(const float4*)(xr + lane * 8);
  float4 v1 = *(const float4*)(xr + lane * 8 + 4);
  float xv[8] = {v0.x, v0.y, v0.z, v0.w, v1.x, v1.y, v1.z, v1.w};
  float s = 0.f, ss = 0.f;
#pragma unroll
  for (int i = 0; i < 8; i++) { s += xv[i]; ss += xv[i] * xv[i]; }
#pragma unroll
  for (int off = 32; off; off >>= 1) { s += __shfl_xor(s, off); ss += __shfl_xor(ss, off); }
  float mean = s * (1.f / DIMc);
  float var = ss * (1.f / DIMc) - mean * mean;
  float r = rsqrtf(var + 1e-5f);
  int c = lane * 8;
  ushort o[8] __attribute__((aligned(16)));
#pragma unroll
  for (int i = 0; i < 8; i++) o[i] = f2bf((xv[i] - mean) * r * w[c + i] + b[c + i]);
  *(uint4*)(out + (size_t)gw * DIMc + c) = *(const uint4*)o;
}

// ------- LayerNorm x2: one read of X, both layers' weights -> two outputs ----
__global__ __launch_bounds__(256) void ln_rows2(const float* __restrict__ X,
    const float* __restrict__ w, const float* __restrict__ b,
    ushort* __restrict__ out0, ushort* __restrict__ out1, int rows) {
  int gw = (int)((blockIdx.x * 256 + threadIdx.x) >> 6);
  int lane = threadIdx.x & 63;
  if (gw >= rows) return;
  const float* xr = X + (size_t)gw * DIMc;
  float4 v0 = *(const float4*)(xr + lane * 8);
  float4 v1 = *(const float4*)(xr + lane * 8 + 4);
  float xv[8] = {v0.x, v0.y, v0.z, v0.w, v1.x, v1.y, v1.z, v1.w};
  float s = 0.f, ss = 0.f;
#pragma unroll
  for (int i = 0; i < 8; i++) { s += xv[i]; ss += xv[i] * xv[i]; }
#pragma unroll
  for (int off = 32; off; off >>= 1) { s += __shfl_xor(s, off); ss += __shfl_xor(ss, off); }
  float mean = s * (1.f / DIMc);
  float var = ss * (1.f / DIMc) - mean * mean;
  float r = rsqrtf(var + 1e-5f);
  int c = lane * 8;
  ushort o[8] __attribute__((aligned(16)));
#pragma unroll
  for (int i = 0; i < 8; i++) o[i] = f2bf((xv[i] - mean) * r * w[c + i] + b[c + i]);
  *(uint4*)(out0 + (size_t)gw * DIMc + c) = *(const uint4*)o;
#pragma unroll
  for (int i = 0; i < 8; i++) o[i] = f2bf((xv[i] - mean) * r * w[DIMc + c + i] + b[DIMc + c + i]);
  *(uint4*)(out1 + (size_t)gw * DIMc + c) = *(const uint4*)o;
}

// ------------- ALL weight transposes for one layer, one launch ----------------
// wid 5 (ffn_w1): 16-col-granular interleave for the shuffle-free gelu epilogue.
__global__ __launch_bounds__(256) void wtrans_all(
    const float* __restrict__ wq, const float* __restrict__ wkv,
    const float* __restrict__ wo, const float* __restrict__ qkv,
    const float* __restrict__ swo, const float* __restrict__ w1,
    const float* __restrict__ w2, ushort* __restrict__ dst, int layer) {
  constexpr int Ks[7]   = {512, 512, 128, 512, 512, 512, 2048};
  constexpr int Ns[7]   = {128, 256, 512, 1536, 512, 4096, 512};
  constexpr int pre[8]  = {0, 64, 192, 256, 1024, 1280, 3328, 4352};
  constexpr int dOff[7] = {0, 65536, 196608, 262144, 1048576, 1310720, 3407872};
  int bid = blockIdx.x;
  int wid = 0;
#pragma unroll
  for (int i = 1; i < 7; i++) wid += (bid >= pre[i]);
  int tileIdx = bid - pre[wid];
  int K = Ks[wid], N = Ns[wid];
  const float* srcs[7] = {wq, wkv, wo, qkv, swo, w1, w2};
  const float* W = srcs[wid] + (size_t)layer * K * N;
  ushort* Wt = dst + dOff[wid];
  int ntx = N / 32;
  int n0 = (tileIdx % ntx) * 32, k0 = (tileIdx / ntx) * 32;
  __shared__ float tile[32][33];
  int tx = threadIdx.x & 31, ty = threadIdx.x >> 5;
#pragma unroll
  for (int i = 0; i < 32; i += 8)
    tile[ty + i][tx] = W[(size_t)(k0 + ty + i) * N + n0 + tx];
  __syncthreads();
  if (wid == 5) {
#pragma unroll
    for (int i = 0; i < 32; i += 8) {
      int nrow = n0 + ty + i;
      int p = nrow & 2047;
      int rowT = ((p >> 4) << 5) + ((nrow < 2048) ? 0 : 16) + (p & 15);
      Wt[(size_t)rowT * K + k0 + tx] = f2bf(tile[tx][ty + i]);
    }
  } else {
#pragma unroll
    for (int i = 0; i < 32; i += 8)
      Wt[(size_t)(n0 + ty + i) * K + k0 + tx] = f2bf(tile[tx][ty + i]);
  }
}

// ------- 128x128 GEMM, BK=64, single-buffer (proven r3 structure) ------------
// MODE 0: outB = bf16(acc + bias)
// MODE 1: resOut = resIn + acc + bias   (fp32)
// MODE 2: fused FFN gate (16-col interleaved w1T): write bf16(a*gelu(g)), N/2.
// MODE 3: self-qkv fused rope+vt.
template<int MODE>
__global__ __launch_bounds__(256) void gemm128(const ushort* __restrict__ A,
    const ushort* __restrict__ Bt, const float* __restrict__ bias,
    const float* __restrict__ resIn, float* __restrict__ resOut,
    ushort* __restrict__ outB, int M, int N, int K,
    const float2* __restrict__ cs, ushort* __restrict__ vt) {
  __shared__ __align__(16) ushort As[128 * 64];
  __shared__ __align__(16) ushort Bs[128 * 64];
  int t = threadIdx.x, wv = t >> 6, lane = t & 63;
  int bm = blockIdx.y, bn = blockIdx.x;
  int fr = lane & 15, g = lane >> 4;
  int wr = (wv >> 1) * 64, wc = (wv & 1) * 64;
  int srow = wv * 32 + (lane >> 3);
  int sslot = lane & 7;
  const ushort* Abase = A + (size_t)(bm * 128) * K;
  const ushort* Bbase = Bt + (size_t)(bn * 128) * K;

  f32x4 acc[4][4] = {};
  for (int k0 = 0; k0 < K; k0 += 64) {
#pragma unroll
    for (int j = 0; j < 4; j++) {
      int r = srow + j * 8;
      int kc = sslot ^ (r & 7);
      gload_lds16(Abase + (size_t)r * K + k0 + kc * 8, As + (wv * 256 + j * 64) * 8);
      gload_lds16(Bbase + (size_t)r * K + k0 + kc * 8, Bs + (wv * 256 + j * 64) * 8);
    }
    __syncthreads();
#pragma unroll
    for (int ks = 0; ks < 2; ks++) {
      bf16x8 af[4], bf[4];
#pragma unroll
      for (int mm = 0; mm < 4; mm++) {
        int row = wr + mm * 16 + fr;
        af[mm] = *(const bf16x8*)(As + row * 64 + (((ks * 4 + g) ^ (row & 7)) * 8));
      }
#pragma unroll
      for (int nn = 0; nn < 4; nn++) {
        int row = wc + nn * 16 + fr;
        bf[nn] = *(const bf16x8*)(Bs + row * 64 + (((ks * 4 + g) ^ (row & 7)) * 8));
      }
#pragma unroll
      for (int mm = 0; mm < 4; mm++)
#pragma unroll
        for (int nn = 0; nn < 4; nn++)
          acc[mm][nn] = __builtin_amdgcn_mfma_f32_16x16x32_bf16(af[mm], bf[nn], acc[mm][nn], 0, 0, 0);
    }
    __syncthreads();
  }

  if (MODE == 2) {
    int NH = N >> 1;
#pragma unroll
    for (int mm = 0; mm < 4; mm++)
#pragma unroll
      for (int np = 0; np < 2; np++) {
        int ocol = bn * 64 + (wc >> 1) + np * 16 + fr;
        float ba = bias[ocol];
        float bg = bias[NH + ocol];
#pragma unroll
        for (int i = 0; i < 4; i++) {
          int gr = bm * 128 + wr + mm * 16 + g * 4 + i;
          float a = acc[mm][np * 2][i] + ba;
          float gv = acc[mm][np * 2 + 1][i] + bg;
          outB[(size_t)gr * NH + ocol] = f2bf(a * gelu_fast(gv));
        }
      }
  } else if (MODE == 3) {
    if (bn * 128 < 1024) {   // q/k block: fused rope (+0.125 scale on q)
#pragma unroll
      for (int mm = 0; mm < 4; mm++)
#pragma unroll
        for (int nn = 0; nn < 4; nn++) {
          int gc = bn * 128 + wc + nn * 16 + fr;
          int d = gc & 63;
          float sc = (gc < 512) ? 0.125f : 1.f;
#pragma unroll
          for (int i = 0; i < 4; i++) {
            int gr = bm * 128 + wr + mm * 16 + g * 4 + i;
            float val = acc[mm][nn][i];
            float prt = __shfl_xor(val, 1);
            float2 csv = cs[(size_t)gr * 64 + d];
            outB[(size_t)gr * N + gc] = f2bf(rope_rot(fr & 1, val, prt, csv) * sc);
          }
        }
    } else {                 // v block: transposed store to vt[b][ch][t]
#pragma unroll
      for (int mm = 0; mm < 4; mm++)
#pragma unroll
        for (int nn = 0; nn < 4; nn++) {
          int gc = bn * 128 + wc + nn * 16 + fr;
          int ch = gc - 1024;
          int gr0 = bm * 128 + wr + mm * 16 + g * 4;
          int bb = gr0 >> 10, t0 = gr0 & 1023;
          uint2 w;
          w.x = packbf2(acc[mm][nn][0], acc[mm][nn][1]);
          w.y = packbf2(acc[mm][nn][2], acc[mm][nn][3]);
          *(uint2*)(vt + ((size_t)bb * 512 + ch) * 1024 + t0) = w;
        }
    }
  } else {
#pragma unroll
    for (int mm = 0; mm < 4; mm++)
#pragma unroll
      for (int nn = 0; nn < 4; nn++)
#pragma unroll
        for (int i = 0; i < 4; i++) {
          int gr = bm * 128 + wr + mm * 16 + g * 4 + i;
          int gc = bn * 128 + wc + nn * 16 + fr;
          float val = acc[mm][nn][i] + (bias ? bias[gc] : 0.f);
          if (MODE == 0) outB[(size_t)gr * N + gc] = f2bf(val);
          else resOut[(size_t)gr * N + gc] = resIn[(size_t)gr * N + gc] + val;
        }
  }
}

// ------- 256x256 GEMM, BK=64, 8-wave 4-phase COUNTED-vmcnt pipeline ----------
// (w1 only; part of the measured-best 621.9 us configuration)
__global__ __launch_bounds__(512, 2) void gemm256_gelu(
    const ushort* __restrict__ A, const ushort* __restrict__ Bt,
    const float* __restrict__ bias, ushort* __restrict__ outB,
    int M, int N, int K) {
  __shared__ __align__(16) ushort As[2][256 * 64];   // 64 KB
  __shared__ __align__(16) ushort Bs[2][256 * 64];   // 64 KB
  int t = threadIdx.x, wv = t >> 6, lane = t & 63;
  int bm = blockIdx.y, bn = blockIdx.x;
  int fr = lane & 15, g = lane >> 4;
  int wr = (wv >> 2) * 128, wc = (wv & 3) * 64;      // 2M x 4N wave grid
  int srow = wv * 32 + (lane >> 3);
  int sslot = lane & 7;
  const ushort* Abase = A + (size_t)(bm * 256) * K;
  const ushort* Bbase = Bt + (size_t)(bn * 256) * K;

  f32x4 acc[8][4] = {};
  int nt = K >> 6;   // 8 for K=512

#define STG256(buf, kt)                                                       \
  {                                                                           \
    _Pragma("unroll")                                                         \
    for (int j = 0; j < 4; j++) {                                             \
      int r = srow + j * 8;                                                   \
      int kc = sslot ^ (r & 7);                                               \
      gload_lds16(Abase + (size_t)r * K + (kt) * 64 + kc * 8,                 \
                  &As[buf][(wv * 256 + j * 64) * 8]);                         \
      gload_lds16(Bbase + (size_t)r * K + (kt) * 64 + kc * 8,                 \
                  &Bs[buf][(wv * 256 + j * 64) * 8]);                         \
    }                                                                         \
  }

  STG256(0, 0);
  STG256(1, 1);

  for (int tt = 0; tt < nt; tt++) {
    int cur = tt & 1;
    if (tt + 1 < nt) asm volatile("s_waitcnt vmcnt(8)" ::: "memory");
    else             asm volatile("s_waitcnt vmcnt(0)" ::: "memory");
    __builtin_amdgcn_s_barrier();
    const ushort* Ac = As[cur];
    const ushort* Bc = Bs[cur];
#pragma unroll
    for (int ph = 0; ph < 4; ph++) {
      const int mh = ph >> 1, nh = ph & 1;
      bf16x8 af[2][4], bf[2][2];
#pragma unroll
      for (int ks = 0; ks < 2; ks++) {
#pragma unroll
        for (int mi = 0; mi < 4; mi++) {
          int row = wr + (mh * 4 + mi) * 16 + fr;
          af[ks][mi] = ds_read8(Ac + row * 64 + (((ks * 4 + g) ^ (row & 7)) * 8));
        }
#pragma unroll
        for (int ni = 0; ni < 2; ni++) {
          int row = wc + (nh * 2 + ni) * 16 + fr;
          bf[ks][ni] = ds_read8(Bc + row * 64 + (((ks * 4 + g) ^ (row & 7)) * 8));
        }
      }
      asm volatile("s_waitcnt lgkmcnt(0)" ::: "memory");
      __builtin_amdgcn_sched_barrier(0);
      __builtin_amdgcn_s_setprio(1);
#pragma unroll
      for (int ks = 0; ks < 2; ks++)
#pragma unroll
        for (int mi = 0; mi < 4; mi++)
#pragma unroll
          for (int ni = 0; ni < 2; ni++)
            acc[mh * 4 + mi][nh * 2 + ni] = __builtin_amdgcn_mfma_f32_16x16x32_bf16(
                af[ks][mi], bf[ks][ni], acc[mh * 4 + mi][nh * 2 + ni], 0, 0, 0);
      __builtin_amdgcn_s_setprio(0);
      __builtin_amdgcn_s_barrier();
    }
    if (tt + 2 < nt) STG256(cur, tt + 2);
  }
#undef STG256

  int NH = N >> 1;
#pragma unroll
  for (int mf = 0; mf < 8; mf++)
#pragma unroll
    for (int np = 0; np < 2; np++) {
      int ocol = bn * 128 + (wc >> 1) + np * 16 + fr;
      float ba = bias[ocol];
      float bg = bias[NH + ocol];
#pragma unroll
      for (int i = 0; i < 4; i++) {
        int gr = bm * 256 + wr + mf * 16 + g * 4 + i;
        float a = acc[mf][np * 2][i] + ba;
        float gv = acc[mf][np * 2 + 1][i] + bg;
        outB[(size_t)gr * NH + ocol] = f2bf(a * gelu_fast(gv));
      }
    }
}

// ------- 128x64 GEMM, BK=64, single-buffer, 24 KB LDS (high occupancy) -------
template<int MODE>
__global__ __launch_bounds__(256) void gemm128x64(const ushort* __restrict__ A,
    const ushort* __restrict__ Bt, const float* __restrict__ bias,
    const float* __restrict__ resIn, float* __restrict__ resOut,
    ushort* __restrict__ outB, int M, int N, int K,
    const float2* __restrict__ cs, ushort* __restrict__ vt) {
  __shared__ __align__(16) ushort As[128 * 64];   // 16 KB
  __shared__ __align__(16) ushort Bs[64 * 64];    //  8 KB
  int t = threadIdx.x, wv = t >> 6, lane = t & 63;
  int bm = blockIdx.y, bn = blockIdx.x;
  int fr = lane & 15, g = lane >> 4;
  int wr = (wv >> 1) * 64, wc = (wv & 1) * 32;
  const ushort* Abase = A + (size_t)(bm * 128) * K;
  const ushort* Bbase = Bt + (size_t)(bn * 64) * K;

  f32x4 acc[4][2] = {};
  for (int k0 = 0; k0 < K; k0 += 64) {
#pragma unroll
    for (int j = 0; j < 4; j++) {
      int c = j * 256 + wv * 64 + lane;
      int r = c >> 3, s = c & 7;
      int kc = s ^ (r & 7);
      gload_lds16(Abase + (size_t)r * K + k0 + kc * 8, As + (j * 256 + wv * 64) * 8);
      if (j < 2)
        gload_lds16(Bbase + (size_t)r * K + k0 + kc * 8, Bs + (j * 256 + wv * 64) * 8);
    }
    __syncthreads();
#pragma unroll
    for (int ks = 0; ks < 2; ks++) {
      bf16x8 af[4], bf[2];
#pragma unroll
      for (int mm = 0; mm < 4; mm++) {
        int row = wr + mm * 16 + fr;
        af[mm] = *(const bf16x8*)(As + row * 64 + (((ks * 4 + g) ^ (row & 7)) * 8));
      }
#pragma unroll
      for (int nn = 0; nn < 2; nn++) {
        int row = wc + nn * 16 + fr;
        bf[nn] = *(const bf16x8*)(Bs + row * 64 + (((ks * 4 + g) ^ (row & 7)) * 8));
      }
#pragma unroll
      for (int mm = 0; mm < 4; mm++)
#pragma unroll
        for (int nn = 0; nn < 2; nn++)
          acc[mm][nn] = __builtin_amdgcn_mfma_f32_16x16x32_bf16(af[mm], bf[nn], acc[mm][nn], 0, 0, 0);
    }
    __syncthreads();
  }

  if (MODE == 3) {
    if (bn * 64 < 128) {     // k block: fused rope (lat table)
#pragma unroll
      for (int mm = 0; mm < 4; mm++)
#pragma unroll
        for (int nn = 0; nn < 2; nn++) {
          int gc = bn * 64 + wc + nn * 16 + fr;
          int d = gc & 63;
#pragma unroll
          for (int i = 0; i < 4; i++) {
            int gr = bm * 128 + wr + mm * 16 + g * 4 + i;
            float val = acc[mm][nn][i];
            float prt = __shfl_xor(val, 1);
            float2 csv = cs[(size_t)gr * 64 + d];
            outB[(size_t)gr * N + gc] = f2bf(rope_rot(fr & 1, val, prt, csv));
          }
        }
    } else {                 // v block: transposed store
#pragma unroll
      for (int mm = 0; mm < 4; mm++)
#pragma unroll
        for (int nn = 0; nn < 2; nn++) {
          int gc = bn * 64 + wc + nn * 16 + fr;
          int ch = gc - 128;
          int gr0 = bm * 128 + wr + mm * 16 + g * 4;
          int bb = gr0 >> 11, t0 = gr0 & 2047;
          uint2 w;
          w.x = packbf2(acc[mm][nn][0], acc[mm][nn][1]);
          w.y = packbf2(acc[mm][nn][2], acc[mm][nn][3]);
          *(uint2*)(vt + ((size_t)bb * 128 + ch) * 2048 + t0) = w;
        }
    }
  } else {
#pragma unroll
    for (int mm = 0; mm < 4; mm++)
#pragma unroll
      for (int nn = 0; nn < 2; nn++)
#pragma unroll
        for (int i = 0; i < 4; i++) {
          int gr = bm * 128 + wr + mm * 16 + g * 4 + i;
          int gc = bn * 64 + wc + nn * 16 + fr;
          float val = acc[mm][nn][i] + (bias ? bias[gc] : 0.f);
          if (MODE == 0) outB[(size_t)gr * N + gc] = f2bf(val);
          else resOut[(size_t)gr * N + gc] = resIn[(size_t)gr * N + gc] + val;
        }
  }
}

// ------- 64x64 GEMM with fused rope (+0.125) epilogue (cross-q only) ---------
__global__ __launch_bounds__(256) void gemm64_rope(const ushort* __restrict__ A,
    const ushort* __restrict__ Bt, ushort* __restrict__ outB,
    const float2* __restrict__ cs, int M, int N, int K) {
  __shared__ __align__(16) ushort As[64][40];
  __shared__ __align__(16) ushort Bs[64][40];
  int t = threadIdx.x;
  int bm = blockIdx.y, bn = blockIdx.x;
  int row = t >> 2, kc = (t & 3) << 3;
  const ushort* aG = A + (size_t)(bm * 64 + row) * K + kc;
  const ushort* bG = Bt + (size_t)(bn * 64 + row) * K + kc;
  int wv = t >> 6, lane = t & 63;
  int wr = (wv >> 1) * 32, wc = (wv & 1) * 32;
  int fr = lane & 15, fk = (lane >> 4) << 3;
  f32x4 acc[2][2] = {};
  for (int k0 = 0; k0 < K; k0 += 32) {
    *(uint4*)&As[row][kc] = *(const uint4*)(aG + k0);
    *(uint4*)&Bs[row][kc] = *(const uint4*)(bG + k0);
    __syncthreads();
    bf16x8 a0 = *(const bf16x8*)&As[wr + fr][fk];
    bf16x8 a1 = *(const bf16x8*)&As[wr + 16 + fr][fk];
    bf16x8 b0 = *(const bf16x8*)&Bs[wc + fr][fk];
    bf16x8 b1 = *(const bf16x8*)&Bs[wc + 16 + fr][fk];
    acc[0][0] = __builtin_amdgcn_mfma_f32_16x16x32_bf16(a0, b0, acc[0][0], 0, 0, 0);
    acc[0][1] = __builtin_amdgcn_mfma_f32_16x16x32_bf16(a0, b1, acc[0][1], 0, 0, 0);
    acc[1][0] = __builtin_amdgcn_mfma_f32_16x16x32_bf16(a1, b0, acc[1][0], 0, 0, 0);
    acc[1][1] = __builtin_amdgcn_mfma_f32_16x16x32_bf16(a1, b1, acc[1][1], 0, 0, 0);
    __syncthreads();
  }
  int cr0 = wr + ((lane >> 4) << 2);
  int cc0 = wc + fr;
#pragma unroll
  for (int mm = 0; mm < 2; mm++)
#pragma unroll
    for (int nn = 0; nn < 2; nn++) {
      int gc = bn * 64 + cc0 + nn * 16;
      int d = gc & 63;
#pragma unroll
      for (int i = 0; i < 4; i++) {
        int gr = bm * 64 + cr0 + mm * 16 + i;
        float val = acc[mm][nn][i];
        float prt = __shfl_xor(val, 1);
        float2 csv = cs[(size_t)gr * 64 + d];
        outB[(size_t)gr * N + gc] = f2bf(rope_rot(fr & 1, val, prt, csv) * 0.125f);
      }
    }
}

// ---------------- MFMA flash attention, swapped operands ---------------------
// (round-10 proven version: direct global->LDS staging, no reg round-trip)
template<int CAUSAL>
__global__ __launch_bounds__(256) void attn_mfma(
    const ushort* __restrict__ Q, const ushort* __restrict__ K,
    const ushort* __restrict__ Vt, ushort* __restrict__ O,
    int qStride, int kStride, int kOff, int oStride,
    int Tq, int NK, int H) {
  __shared__ __align__(16) ushort Ks[64 * 64];
  __shared__ __align__(16) ushort Vs[64 * 64];
  __shared__ __align__(16) ushort Ps[4][16 * 72];
  int b = blockIdx.z, h = blockIdx.y;
  int qt = CAUSAL ? ((int)gridDim.x - 1 - (int)blockIdx.x) : blockIdx.x;
  int t = threadIdx.x, wv = t >> 6, lane = t & 63;
  int g = lane >> 4, fr = lane & 15;
  int qw = qt * 64 + wv * 16;
  int HD = H * 64;

  const ushort* qrow = Q + (size_t)(b * Tq + qw + fr) * qStride + h * 64;
  bf16x8 qlo = *(const bf16x8*)(qrow + g * 8);
  bf16x8 qhi = *(const bf16x8*)(qrow + 32 + g * 8);

  f32x4 o_acc[4] = {};
  float m_run = -1e30f, l_run = 0.f;

  uint32_t* Pw = (uint32_t*)&Ps[wv][0];
  int ntiles = CAUSAL ? (qt + 1) : (NK / 64);
  for (int kt = 0; kt < ntiles; kt++) {
    int k0 = kt * 64;
    __syncthreads();
#pragma unroll
    for (int i = 0; i < 2; i++) {
      int id = t + i * 256;
      int r = id >> 3, c = id & 7;
      uint4 kval = *(const uint4*)(K + (size_t)(b * NK + k0 + r) * kStride + kOff + h * 64 + c * 8);
      *(uint4*)(Ks + r * 64 + ((c ^ (r & 7)) * 8)) = kval;
      uint4 vval = *(const uint4*)(Vt + ((size_t)b * HD + h * 64 + r) * NK + k0 + c * 8);
      *(uint4*)(Vs + r * 64 + ((c ^ (r & 7)) * 8)) = vval;
    }
    __syncthreads();

    f32x4 s[4];
#pragma unroll
    for (int nn = 0; nn < 4; nn++) {
      int row = nn * 16 + fr;
      bf16x8 kf0 = *(const bf16x8*)(Ks + row * 64 + ((g ^ (fr & 7)) * 8));
      bf16x8 kf1 = *(const bf16x8*)(Ks + row * 64 + (((4 + g) ^ (fr & 7)) * 8));
      f32x4 z = {};
      z = __builtin_amdgcn_mfma_f32_16x16x32_bf16(kf0, qlo, z, 0, 0, 0);
      z = __builtin_amdgcn_mfma_f32_16x16x32_bf16(kf1, qhi, z, 0, 0, 0);
      s[nn] = z;
    }
    if (CAUSAL && (k0 + 63 > qw)) {
#pragma unroll
      for (int nn = 0; nn < 4; nn++)
#pragma unroll
        for (int i = 0; i < 4; i++)
          if (k0 + nn * 16 + g * 4 + i > qw + fr) s[nn][i] = -1e30f;
    }
    float tm = s[0][0];
#pragma unroll
    for (int nn = 0; nn < 4; nn++)
#pragma unroll
      for (int i = 0; i < 4; i++) tm = fmaxf(tm, s[nn][i]);
    tm = fmaxf(tm, __shfl_xor(tm, 16));
    tm = fmaxf(tm, __shfl_xor(tm, 32));
    float mnew = fmaxf(m_run, tm);
    float corr = __expf(m_run - mnew);
    float ps = 0.f;
#pragma unroll
    for (int nn = 0; nn < 4; nn++)
#pragma unroll
      for (int i = 0; i < 4; i++) {
        float p = __expf(s[nn][i] - mnew);
        s[nn][i] = p;
        ps += p;
      }
    ps += __shfl_xor(ps, 16);
    ps += __shfl_xor(ps, 32);
    l_run = l_run * corr + ps;
    m_run = mnew;
#pragma unroll
    for (int dd = 0; dd < 4; dd++) o_acc[dd] *= corr;
#pragma unroll
    for (int nn = 0; nn < 4; nn++)
#pragma unroll
      for (int p = 0; p < 2; p++)
        Pw[fr * 36 + 8 * nn + 2 * g + p] = packbf2(s[nn][2 * p], s[nn][2 * p + 1]);
    bf16x8 pa0 = *(const bf16x8*)(&Ps[wv][fr * 72 + g * 8]);
    bf16x8 pa1 = *(const bf16x8*)(&Ps[wv][fr * 72 + 32 + g * 8]);
#pragma unroll
    for (int dd = 0; dd < 4; dd++) {
      int row = dd * 16 + fr;
      bf16x8 vf0 = *(const bf16x8*)(Vs + row * 64 + ((g ^ (fr & 7)) * 8));
      bf16x8 vf1 = *(const bf16x8*)(Vs + row * 64 + (((4 + g) ^ (fr & 7)) * 8));
      o_acc[dd] = __builtin_amdgcn_mfma_f32_16x16x32_bf16(vf0, pa0, o_acc[dd], 0, 0, 0);
      o_acc[dd] = __builtin_amdgcn_mfma_f32_16x16x32_bf16(vf1, pa1, o_acc[dd], 0, 0, 0);
    }
  }
  float rl = 1.f / l_run;
  ushort* obase = O + (size_t)(b * Tq + qw + fr) * oStride + h * 64;
#pragma unroll
  for (int dd = 0; dd < 4; dd++) {
    uint2 w;
    w.x = packbf2(o_acc[dd][0] * rl, o_acc[dd][1] * rl);
    w.y = packbf2(o_acc[dd][2] * rl, o_acc[dd][3] * rl);
    *(uint2*)(obase + dd * 16 + g * 4) = w;
  }
}

// ---------------- orchestration ----------------------------------------------
extern "C" void kernel_launch(void* const* d_in, const int* in_sizes, int n_in,
                              void* d_out, int out_size, void* d_ws, size_t ws_size,
                              hipStream_t stream) {
  const float* bin_queries = (const float*)d_in[0];
  const float* bin_time    = (const float*)d_in[1];
  const float* latents     = (const float*)d_in[2];
  const float* lat_time    = (const float*)d_in[3];
  const float* ca_lnq_w = (const float*)d_in[4];
  const float* ca_lnq_b = (const float*)d_in[5];
  const float* ca_lnc_w = (const float*)d_in[6];
  const float* ca_lnc_b = (const float*)d_in[7];
  const float* ca_wq  = (const float*)d_in[8];
  const float* ca_wkv = (const float*)d_in[9];
  const float* ca_wo  = (const float*)d_in[10];
  const float* ca_bo  = (const float*)d_in[11];
  const float* sa_ln_w = (const float*)d_in[12];
  const float* sa_ln_b = (const float*)d_in[13];
  const float* sa_wqkv = (const float*)d_in[14];
  const float* sa_wo   = (const float*)d_in[15];
  const float* sa_bo   = (const float*)d_in[16];
  const float* ffn_ln_w = (const float*)d_in[17];
  const float* ffn_ln_b = (const float*)d_in[18];
  const float* ffn_w1 = (const float*)d_in[19];
  const float* ffn_b1 = (const float*)d_in[20];
  const float* ffn_w2 = (const float*)d_in[21];
  const float* ffn_b2 = (const float*)d_in[22];

  constexpr size_t X_BYTES = (size_t)RQ * DIMc * 4;
  char* ws = (char*)d_ws;
  float* x = (float*)ws;
  char* A0 = ws + X_BYTES;
  // cross-attn phase
  ushort* cn     = (ushort*)(A0);               // layer-0 cn (arena, reused later)
  ushort* ca_xn  = (ushort*)(A0 + 16777216);
  ushort* qbuf   = (ushort*)(A0 + 25165824);
  ushort* kv     = (ushort*)(A0 + 27262976);
  ushort* ca_att = (ushort*)(A0 + 35651584);
  ushort* vt_c   = (ushort*)(A0 + 37748736);
  // self-attn phase (reuses arena)
  ushort* sa_xn  = (ushort*)(A0);
  ushort* qkv    = (ushort*)(A0 + 8388608);
  ushort* sa_att = (ushort*)(A0 + 33554432);
  ushort* vt_s   = (ushort*)(A0 + 41943040);
  // ffn phase (reuses arena)
  ushort* hb     = (ushort*)(A0);
  ushort* ag     = (ushort*)(A0 + 8388608);
  // persistent region (never overwritten by phase arena)
  float2* csQ = (float2*)(A0 + 62914560);   // 4 MB
  float2* csL = (float2*)(A0 + 67108864);   // 8 MB
  ushort* cn2 = (ushort*)(A0 + 79691776);   // 16 MB (layer-1 cn)
  // bf16 transposed weights for the current layer
  char* W0 = A0 + 109051904;
  ushort* wbase = (ushort*)W0;
  ushort* wqT  = wbase;
  ushort* wkvT = wbase + 65536;
  ushort* woT  = wbase + 196608;
  ushort* qkvT = wbase + 262144;
  ushort* swoT = wbase + 1048576;
  ushort* w1T  = wbase + 1310720;
  ushort* w2T  = wbase + 3407872;

  trig_prep<<<(RQ * 64) / 256, 256, 0, stream>>>(bin_time, csQ, RQ * 64);
  trig_prep<<<(RL * 64) / 256, 256, 0, stream>>>(lat_time, csL, RL * 64);
  // both layers' latent LN in one pass over latents
  ln_rows2<<<RL / 4, 256, 0, stream>>>(latents, ca_lnc_w, ca_lnc_b, cn, cn2, RL);

  for (int l = 0; l < 2; l++) {
    wtrans_all<<<4352, 256, 0, stream>>>(ca_wq, ca_wkv, ca_wo, sa_wqkv, sa_wo,
                                         ffn_w1, ffn_w2, wbase, l);

    // ---- cross attention ----
    const float* xin = (l == 0) ? bin_queries : x;
    const ushort* cnl = (l == 0) ? cn : cn2;
    ln_rows<<<RQ / 4, 256, 0, stream>>>(xin, ca_lnq_w + l * DIMc, ca_lnq_b + l * DIMc, ca_xn, RQ);
    gemm64_rope<<<dim3(CIc / 64, RQ / 64), 256, 0, stream>>>(ca_xn, wqT, qbuf, csQ, RQ, CIc, DIMc);
    gemm128x64<3><<<dim3(2 * CIc / 64, RL / 128), 256, 0, stream>>>(cnl, wkvT, nullptr,
        nullptr, nullptr, kv, RL, 2 * CIc, DIMc, csL, vt_c);
    attn_mfma<0><<<dim3(Tc / 64, CHc, Bc), 256, 0, stream>>>(qbuf, kv, vt_c, ca_att,
        CIc, 2 * CIc, 0, CIc, Tc, Nc, CHc);
    gemm128x64<1><<<dim3(DIMc / 64, RQ / 128), 256, 0, stream>>>(ca_att, woT, ca_bo + l * DIMc,
        xin, x, nullptr, RQ, DIMc, CIc, nullptr, nullptr);

    // ---- self attention (causal) ----
    ln_rows<<<RQ / 4, 256, 0, stream>>>(x, sa_ln_w + l * DIMc, sa_ln_b + l * DIMc, sa_xn, RQ);
    gemm128<3><<<dim3(3 * SIc / 128, RQ / 128), 256, 0, stream>>>(sa_xn, qkvT, nullptr,
        nullptr, nullptr, qkv, RQ, 3 * SIc, DIMc, csQ, vt_s);
    attn_mfma<1><<<dim3(Tc / 64, SHc, Bc), 256, 0, stream>>>(qkv, qkv, vt_s, sa_att,
        3 * SIc, 3 * SIc, SIc, SIc, Tc, Tc, SHc);
    gemm128x64<1><<<dim3(DIMc / 64, RQ / 128), 256, 0, stream>>>(sa_att, swoT, sa_bo + l * DIMc,
        x, x, nullptr, RQ, DIMc, SIc, nullptr, nullptr);

    // ---- FFN: w1 on the 8-wave counted-vmcnt 256x256 pipeline ----
    ln_rows<<<RQ / 4, 256, 0, stream>>>(x, ffn_ln_w + l * DIMc, ffn_ln_b + l * DIMc, hb, RQ);
    gemm256_gelu<<<dim3(2 * FFc / 256, RQ / 256), 512, 0, stream>>>(hb, w1T,
        ffn_b1 + (size_t)l * 2 * FFc, ag, RQ, 2 * FFc, DIMc);
    float* resOut = (l == 1) ? (float*)d_out : x;
    gemm128x64<1><<<dim3(DIMc / 64, RQ / 128), 256, 0, stream>>>(ag, w2T, ffn_b2 + l * DIMc,
        x, resOut, nullptr, RQ, DIMc, FFc, nullptr, nullptr);
  }
}